// Round 1
// 647.012 us; speedup vs baseline: 1.2789x; 1.2789x over previous
//
#include <hip/hip_runtime.h>

#define N_NODES 100000
#define N_EDGES 1600000

typedef __attribute__((ext_vector_type(8))) _Float16 half8;
typedef __attribute__((ext_vector_type(4))) _Float16 half4v;
typedef __attribute__((ext_vector_type(4))) float floatx4;

// ---------------- CSR build ----------------
// Pass 1: degree count + per-edge rank (removes atomics from the fill pass).

__global__ void deg_rank(const int* __restrict__ dst, int* __restrict__ deg,
                         int* __restrict__ rank, int e) {
    int i = blockIdx.x * blockDim.x + threadIdx.x;
    if (i < e) rank[i] = atomicAdd(&deg[dst[i]], 1);
}

// Multi-block exclusive scan of deg -> offs (replaces single-block scan_kernel).
// Chunk = 2048 elements per block (256 threads x 8). NB = ceil(N/2048) = 49.

__global__ __launch_bounds__(256) void scan_partial(const int* __restrict__ deg,
                                                    int* __restrict__ bsum, int n) {
    __shared__ int wsum[4];
    int t = threadIdx.x;
    int base = blockIdx.x * 2048 + t * 8;
    int tsum = 0;
    #pragma unroll
    for (int k = 0; k < 8; ++k) {
        int idx = base + k;
        tsum += (idx < n) ? deg[idx] : 0;
    }
    #pragma unroll
    for (int d = 1; d < 64; d <<= 1) tsum += __shfl_xor(tsum, d, 64);
    if ((t & 63) == 0) wsum[t >> 6] = tsum;
    __syncthreads();
    if (t == 0) bsum[blockIdx.x] = wsum[0] + wsum[1] + wsum[2] + wsum[3];
}

// Single wave scans the (<=64) block sums; bbase[nb] = grand total.
__global__ void scan_blocksums(const int* __restrict__ bsum, int* __restrict__ bbase, int nb) {
    int t = threadIdx.x;               // 64 threads
    int v = (t < nb) ? bsum[t] : 0;
    int s = v;
    #pragma unroll
    for (int d = 1; d < 64; d <<= 1) {
        int u = __shfl_up(s, d, 64);
        if (t >= d) s += u;
    }
    if (t < nb) bbase[t] = s - v;
    if (t == 63) bbase[nb] = s;
}

__global__ __launch_bounds__(256) void scan_write(const int* __restrict__ deg,
                                                  const int* __restrict__ bbase,
                                                  int* __restrict__ offs, int n, int nb) {
    __shared__ int wsum[4];
    int t = threadIdx.x;
    int lane = t & 63, w = t >> 6;
    int base = blockIdx.x * 2048 + t * 8;
    int v[8];
    #pragma unroll
    for (int k = 0; k < 8; ++k) {
        int idx = base + k;
        v[k] = (idx < n) ? deg[idx] : 0;
    }
    int tsum = 0;
    #pragma unroll
    for (int k = 0; k < 8; ++k) { int x = v[k]; v[k] = tsum; tsum += x; }  // v[k]=excl in thread
    int s = tsum;
    #pragma unroll
    for (int d = 1; d < 64; d <<= 1) {
        int u = __shfl_up(s, d, 64);
        if (lane >= d) s += u;
    }
    if (lane == 63) wsum[w] = s;
    __syncthreads();
    int wb = 0;
    for (int j = 0; j < w; ++j) wb += wsum[j];
    int texcl = bbase[blockIdx.x] + wb + (s - tsum);
    #pragma unroll
    for (int k = 0; k < 8; ++k) {
        int idx = base + k;
        if (idx < n) offs[idx] = texcl + v[k];
    }
    if (blockIdx.x == 0 && t == 0) offs[n] = bbase[nb];
}

// Pass 2: atomic-free CSR fill using precomputed ranks.
__global__ void fill_csr2(const int* __restrict__ src, const int* __restrict__ dst,
                          const int* __restrict__ offs, const int* __restrict__ rank,
                          int* __restrict__ csr, int e) {
    int i = blockIdx.x * blockDim.x + threadIdx.x;
    if (i < e) csr[offs[dst[i]] + rank[i]] = src[i];
}

// ---------------- x -> fp16 convert ----------------

__global__ void cvt_f16(const float4* __restrict__ in, half4v* __restrict__ oh, int n4) {
    int i = blockIdx.x * blockDim.x + threadIdx.x;
    if (i >= n4) return;
    float4 v = in[i];
    half4v h;
    h[0] = (_Float16)v.x; h[1] = (_Float16)v.y;
    h[2] = (_Float16)v.z; h[3] = (_Float16)v.w;
    oh[i] = h;
}

// ---------------- fused weight prep (all 6 weights, one launch) ----------------
// W[K][dout] fp32 -> Wt[npad][K] fp16.
// NOTE: 12288 is NOT a power of two -- use subtraction, never masking (r8 bug).

__global__ void prep_all(const float* __restrict__ ws1, const float* __restrict__ wn1,
                         const float* __restrict__ ws2, const float* __restrict__ wn2,
                         const float* __restrict__ ws3, const float* __restrict__ wn3,
                         _Float16* __restrict__ o1s, _Float16* __restrict__ o1n,
                         _Float16* __restrict__ o2s, _Float16* __restrict__ o2n,
                         _Float16* __restrict__ o3c) {
    int i = blockIdx.x * blockDim.x + threadIdx.x;
    if (i < 65536) {
        const float* W = (i < 32768) ? ws1 : wn1;
        _Float16* O = (i < 32768) ? o1s : o1n;
        int j = i & 32767;                         // 32768 = 2^15, mask ok
        int nn = j >> 7, k = j & 127;              // K=128, dout=256
        O[j] = (_Float16)W[k * 256 + nn];
    } else if (i < 196608) {
        int j = i - 65536;
        const float* W = (j < 65536) ? ws2 : wn2;
        _Float16* O = (j < 65536) ? o2s : o2n;
        j &= 65535;                                // 65536 = 2^16, mask ok
        int nn = j >> 8, k = j & 255;              // K=256, dout=256
        O[j] = (_Float16)W[k * 256 + nn];
    } else if (i < 221184) {
        int j = i - 196608;                        // [0, 24576)
        const float* W = (j < 12288) ? ws3 : wn3;
        _Float16* O = o3c + ((j < 12288) ? 0 : 12288);
        j = (j < 12288) ? j : j - 12288;           // FIX: 12288 not pow2, subtract
        int nn = j >> 8, k = j & 255;              // K=256, dout=47, npad=48
        O[j] = (nn < 47) ? (_Float16)W[k * 47 + nn] : (_Float16)0.f;
    }
}

// ---------------- mean aggregation (fp16 gather, fp32 accumulate, fp16 out) ----------
// Multi-row gathers: sub-wave groups each fetch a DIFFERENT edge's row per
// iteration (16 B/lane dwordx4). Loop unrolled so each sub-wave keeps
// MULTIPLE rows in flight (latency-bound: VGPR_Count was 16, lots of headroom).

// D=256: wave per node; half-waves handle edges; 4 rows in flight per half-wave.
__global__ __launch_bounds__(256) void agg256h(const _Float16* __restrict__ Hh,
                                               const int* __restrict__ csr,
                                               const int* __restrict__ offs,
                                               _Float16* __restrict__ Ph, int n) {
    int node = blockIdx.x * 4 + (threadIdx.x >> 6);
    int lane = threadIdx.x & 63;
    int hf = lane >> 5;
    int sl = lane & 31;
    if (node >= n) return;
    int e0 = offs[node], e1 = offs[node + 1];
    float a[8] = {0.f, 0.f, 0.f, 0.f, 0.f, 0.f, 0.f, 0.f};
    int e = e0;
    for (; e + 8 <= e1; e += 8) {
        int s0 = csr[e + hf];
        int s1 = csr[e + 2 + hf];
        int s2 = csr[e + 4 + hf];
        int s3 = csr[e + 6 + hf];
        half8 u0 = ((const half8*)(Hh + (size_t)s0 * 256))[sl];
        half8 u1 = ((const half8*)(Hh + (size_t)s1 * 256))[sl];
        half8 u2 = ((const half8*)(Hh + (size_t)s2 * 256))[sl];
        half8 u3 = ((const half8*)(Hh + (size_t)s3 * 256))[sl];
        #pragma unroll
        for (int j = 0; j < 8; ++j) a[j] += (float)u0[j];
        #pragma unroll
        for (int j = 0; j < 8; ++j) a[j] += (float)u1[j];
        #pragma unroll
        for (int j = 0; j < 8; ++j) a[j] += (float)u2[j];
        #pragma unroll
        for (int j = 0; j < 8; ++j) a[j] += (float)u3[j];
    }
    for (; e + 2 <= e1; e += 2) {
        int s = csr[e + hf];
        half8 u = ((const half8*)(Hh + (size_t)s * 256))[sl];
        #pragma unroll
        for (int j = 0; j < 8; ++j) a[j] += (float)u[j];
    }
    if (e < e1 && hf == 0) {
        int s = csr[e];
        half8 u = ((const half8*)(Hh + (size_t)s * 256))[sl];
        #pragma unroll
        for (int j = 0; j < 8; ++j) a[j] += (float)u[j];
    }
    #pragma unroll
    for (int j = 0; j < 8; ++j) a[j] += __shfl_xor(a[j], 32);
    if (hf == 0) {
        float inv = 1.0f / fmaxf((float)(e1 - e0), 1.0f);
        half8 rh;
        #pragma unroll
        for (int j = 0; j < 8; ++j) rh[j] = (_Float16)(a[j] * inv);
        ((half8*)(Ph + (size_t)node * 256))[sl] = rh;
    }
}

// D=128: wave per node; quarter-waves handle edges; 2 rows in flight per quarter.
__global__ __launch_bounds__(256) void agg128h(const _Float16* __restrict__ xh,
                                               const int* __restrict__ csr,
                                               const int* __restrict__ offs,
                                               _Float16* __restrict__ Ph, int n) {
    int node = blockIdx.x * 4 + (threadIdx.x >> 6);
    int lane = threadIdx.x & 63;
    int qtr = lane >> 4;
    int sl = lane & 15;
    if (node >= n) return;
    int e0 = offs[node], e1 = offs[node + 1];
    float a[8] = {0.f, 0.f, 0.f, 0.f, 0.f, 0.f, 0.f, 0.f};
    int e = e0;
    for (; e + 8 <= e1; e += 8) {
        int s0 = csr[e + qtr];
        int s1 = csr[e + 4 + qtr];
        half8 u0 = ((const half8*)(xh + (size_t)s0 * 128))[sl];
        half8 u1 = ((const half8*)(xh + (size_t)s1 * 128))[sl];
        #pragma unroll
        for (int j = 0; j < 8; ++j) a[j] += (float)u0[j];
        #pragma unroll
        for (int j = 0; j < 8; ++j) a[j] += (float)u1[j];
    }
    for (; e + 4 <= e1; e += 4) {
        int s = csr[e + qtr];
        half8 u = ((const half8*)(xh + (size_t)s * 128))[sl];
        #pragma unroll
        for (int j = 0; j < 8; ++j) a[j] += (float)u[j];
    }
    int rem = e1 - e;
    if (qtr < rem) {
        int s = csr[e + qtr];
        half8 u = ((const half8*)(xh + (size_t)s * 128))[sl];
        #pragma unroll
        for (int j = 0; j < 8; ++j) a[j] += (float)u[j];
    }
    #pragma unroll
    for (int j = 0; j < 8; ++j) {
        a[j] += __shfl_xor(a[j], 16);
        a[j] += __shfl_xor(a[j], 32);
    }
    if (lane < 16) {
        float inv = 1.0f / fmaxf((float)(e1 - e0), 1.0f);
        half8 rh;
        #pragma unroll
        for (int j = 0; j < 8; ++j) rh[j] = (_Float16)(a[j] * inv);
        ((half8*)(Ph + (size_t)node * 128))[sl] = rh;
    }
}

// Layer-3 finish: out[node][0:47] = S[node] + mean(Y[nbrs]); wave per node,
// quarter-waves, 2 rows in flight per quarter; Y rows 96 B fp16.
__global__ __launch_bounds__(256) void agg_l3(const _Float16* __restrict__ Y,
                                              const float* __restrict__ S,
                                              const int* __restrict__ csr,
                                              const int* __restrict__ offs,
                                              float* __restrict__ out, int n) {
    int node = blockIdx.x * 4 + (threadIdx.x >> 6);
    int lane = threadIdx.x & 63;
    int qtr = lane >> 4;
    int sl = lane & 15;
    int c = sl < 12 ? sl : 11;
    if (node >= n) return;
    int e0 = offs[node], e1 = offs[node + 1];
    float a0 = 0.f, a1 = 0.f, a2 = 0.f, a3 = 0.f;
    int e = e0;
    for (; e + 8 <= e1; e += 8) {
        int s0 = csr[e + qtr];
        int s1 = csr[e + 4 + qtr];
        half4v f0 = ((const half4v*)(Y + (size_t)s0 * 48))[c];
        half4v f1 = ((const half4v*)(Y + (size_t)s1 * 48))[c];
        a0 += (float)f0[0] + (float)f1[0];
        a1 += (float)f0[1] + (float)f1[1];
        a2 += (float)f0[2] + (float)f1[2];
        a3 += (float)f0[3] + (float)f1[3];
    }
    for (; e + 4 <= e1; e += 4) {
        int s = csr[e + qtr];
        half4v f = ((const half4v*)(Y + (size_t)s * 48))[c];
        a0 += (float)f[0]; a1 += (float)f[1]; a2 += (float)f[2]; a3 += (float)f[3];
    }
    int rem = e1 - e;
    if (qtr < rem) {
        int s = csr[e + qtr];
        half4v f = ((const half4v*)(Y + (size_t)s * 48))[c];
        a0 += (float)f[0]; a1 += (float)f[1]; a2 += (float)f[2]; a3 += (float)f[3];
    }
    a0 += __shfl_xor(a0, 16); a0 += __shfl_xor(a0, 32);
    a1 += __shfl_xor(a1, 16); a1 += __shfl_xor(a1, 32);
    a2 += __shfl_xor(a2, 16); a2 += __shfl_xor(a2, 32);
    a3 += __shfl_xor(a3, 16); a3 += __shfl_xor(a3, 32);
    if (lane < 12) {
        float inv = 1.0f / fmaxf((float)(e1 - e0), 1.0f);
        float4 sv = ((const float4*)(S + (size_t)node * 48))[c];
        float r[4] = {sv.x + a0 * inv, sv.y + a1 * inv, sv.z + a2 * inv, sv.w + a3 * inv};
        #pragma unroll
        for (int k = 0; k < 4; ++k) {
            int col = c * 4 + k;
            if (col < 47) out[(size_t)node * 47 + col] = r[k];
        }
    }
}

// ---------------- MFMA GEMM (plain fp16, A direct-from-global) -------------
// out[128 x dout] = A1@W1 (+ A2@W2) + b (+relu), fp32 accumulate.
// Each wave owns rows [bm+w*32, bm+w*32+32): A frags are direct 16B global loads
// (no A staging; in-place layer 2 safe). B staged in LDS (LDT=36, conflict-free)
// with register prefetch of step s+1 issued after the barrier.
// OUTFMT 1: fp16 H write (dout=256). OUTFMT 2: cols 0-47 -> S fp32 (+bias),
// cols 48-95 -> Y fp16 (stride 48).

template <int NTILES, int OUTFMT>
__global__ __launch_bounds__(256, 2) void gemm_mfma(
    const _Float16* __restrict__ A1h, const _Float16* __restrict__ A2h,
    const _Float16* __restrict__ W1, const _Float16* __restrict__ W2,
    const float* __restrict__ bias, float* __restrict__ outS, _Float16* __restrict__ outY,
    _Float16* __restrict__ outh, int n, int K, int dout, int relu, int phases) {
    constexpr int NPAD = NTILES * 16;
    constexpr int LDT = 36;
    __shared__ _Float16 Bs[NPAD * LDT];

    const int t = threadIdx.x;
    const int bm = blockIdx.x * 128;
    const int lane = t & 63;
    const int w = t >> 6;
    const int quad = lane >> 4;
    const int tl = lane & 15;
    const int r0 = bm + w * 32 + tl;
    const int r1 = r0 + 16;

    floatx4 acc[2][NTILES];
    #pragma unroll
    for (int i = 0; i < 2; ++i)
        #pragma unroll
        for (int j = 0; j < NTILES; ++j) acc[i][j] = (floatx4){0.f, 0.f, 0.f, 0.f};

    const int spp = K >> 5;
    const int nsteps = phases * spp;

    half8 pb0, pb1, pb2, pb3;
    half8 pah0 = {0}, pah1 = {0};

    if (t < NPAD) {
        const half8* p = (const half8*)(W1 + (size_t)t * K);
        pb0 = p[0]; pb1 = p[1]; pb2 = p[2]; pb3 = p[3];
    }
    {
        int kq = quad * 8;
        if (r0 < n) pah0 = *(const half8*)(A1h + (size_t)r0 * K + kq);
        if (r1 < n) pah1 = *(const half8*)(A1h + (size_t)r1 * K + kq);
    }

    for (int s = 0; s < nsteps; ++s) {
        __syncthreads();
        if (t < NPAD) {
            *(half8*)&Bs[t * LDT + 0]  = pb0;
            *(half8*)&Bs[t * LDT + 8]  = pb1;
            *(half8*)&Bs[t * LDT + 16] = pb2;
            *(half8*)&Bs[t * LDT + 24] = pb3;
        }
        __syncthreads();
        half8 ah0 = pah0, ah1 = pah1;
        if (s + 1 < nsteps) {
            int s2 = s + 1;
            int ph2 = (s2 >= spp) ? 1 : 0;
            int k02 = (ph2 ? s2 - spp : s2) << 5;
            if (t < NPAD) {
                const _Float16* W = ph2 ? W2 : W1;
                const half8* p = (const half8*)(W + (size_t)t * K + k02);
                pb0 = p[0]; pb1 = p[1]; pb2 = p[2]; pb3 = p[3];
            }
            const _Float16* Ah = ph2 ? A2h : A1h;
            int kq = k02 + quad * 8;
            pah0 = (half8){0}; pah1 = (half8){0};
            if (r0 < n) pah0 = *(const half8*)(Ah + (size_t)r0 * K + kq);
            if (r1 < n) pah1 = *(const half8*)(Ah + (size_t)r1 * K + kq);
        }
        #pragma unroll
        for (int nt = 0; nt < NTILES; ++nt) {
            half8 bh = *(const half8*)&Bs[(nt * 16 + tl) * LDT + quad * 8];
            acc[0][nt] = __builtin_amdgcn_mfma_f32_16x16x32_f16(ah0, bh, acc[0][nt], 0, 0, 0);
            acc[1][nt] = __builtin_amdgcn_mfma_f32_16x16x32_f16(ah1, bh, acc[1][nt], 0, 0, 0);
        }
    }

    #pragma unroll
    for (int mt = 0; mt < 2; ++mt) {
        #pragma unroll
        for (int nt = 0; nt < NTILES; ++nt) {
            int gc = nt * 16 + tl;
            if (OUTFMT == 1 && gc >= dout) continue;
            #pragma unroll
            for (int r = 0; r < 4; ++r) {
                int gr = bm + w * 32 + mt * 16 + quad * 4 + r;
                if (gr >= n) continue;
                float v = acc[mt][nt][r];
                if (OUTFMT == 1) {
                    v += bias[gc];
                    if (relu) v = fmaxf(v, 0.f);
                    outh[(size_t)gr * 256 + gc] = (_Float16)v;
                } else {
                    if (gc < 48) {
                        v += (gc < 47) ? bias[gc] : 0.f;
                        outS[(size_t)gr * 48 + gc] = v;
                    } else {
                        outY[(size_t)gr * 48 + (gc - 48)] = (_Float16)v;
                    }
                }
            }
        }
    }
}

extern "C" void kernel_launch(void* const* d_in, const int* in_sizes, int n_in,
                              void* d_out, int out_size, void* d_ws, size_t ws_size,
                              hipStream_t stream) {
    (void)in_sizes; (void)n_in; (void)out_size; (void)ws_size;
    const int N = N_NODES, E = N_EDGES;
    const float* x = (const float*)d_in[0];
    const int* src = (const int*)d_in[1];
    const int* dst = (const int*)d_in[2];
    const float* w_self1 = (const float*)d_in[3];
    const float* w_neigh1 = (const float*)d_in[4];
    const float* b1 = (const float*)d_in[5];
    const float* w_self2 = (const float*)d_in[6];
    const float* w_neigh2 = (const float*)d_in[7];
    const float* b2 = (const float*)d_in[8];
    const float* w_self3 = (const float*)d_in[9];
    const float* w_neigh3 = (const float*)d_in[10];
    const float* b3 = (const float*)d_in[11];
    float* out = (float*)d_out;

    // workspace layout (~110 MB)
    _Float16* Ph = (_Float16*)d_ws;             // N*256 fp16 (agg; N*128 in L1)
    _Float16* Hh = Ph + (size_t)N * 256;        // N*256 fp16 (hidden)
    int* deg = (int*)(Hh + (size_t)N * 256);    // N
    int* offs = deg + N;                        // N+4
    int* csr = offs + N + 4;                    // E
    _Float16* wbuf = (_Float16*)(csr + E);
    _Float16* w1s = wbuf;                       // 256*128
    _Float16* w1n = w1s + 32768;                // 256*128
    _Float16* w2s = w1n + 32768;                // 256*256
    _Float16* w2n = w2s + 65536;                // 256*256
    _Float16* w3c = w2n + 65536;                // 96*256 combined [self|neigh]
    int* bsum = (int*)(w3c + 24576);            // 64
    int* bbase = bsum + 64;                     // NB+1
    // overlays on the Ph region:
    int* rank = (int*)Ph;                       // E ints, bytes [0, 6.4MB): dead
                                                // before agg128h writes Ph
    _Float16* xh = Ph + (size_t)N * 128;        // N*128 fp16 (layer 1, upper half)
    float* S = (float*)Ph;                      // N*48 fp32 (layer 3; P dead)
    _Float16* Y = (_Float16*)(S + (size_t)N * 48);  // N*48 fp16

    const int NB = (N + 2047) / 2048;           // 49 scan blocks

    hipMemsetAsync(deg, 0, N * sizeof(int), stream);
    deg_rank<<<(E + 255) / 256, 256, 0, stream>>>(dst, deg, rank, E);
    scan_partial<<<NB, 256, 0, stream>>>(deg, bsum, N);
    scan_blocksums<<<1, 64, 0, stream>>>(bsum, bbase, NB);
    scan_write<<<NB, 256, 0, stream>>>(deg, bbase, offs, N, NB);
    fill_csr2<<<(E + 255) / 256, 256, 0, stream>>>(src, dst, offs, rank, csr, E);

    cvt_f16<<<(N * 128 / 4 + 255) / 256, 256, 0, stream>>>((const float4*)x, (half4v*)xh,
                                                           N * 128 / 4);
    prep_all<<<(221184 + 255) / 256, 256, 0, stream>>>(w_self1, w_neigh1, w_self2, w_neigh2,
                                                       w_self3, w_neigh3, w1s, w1n, w2s, w2n,
                                                       w3c);

    int gemmGrid = (N + 127) / 128;
    int aggGrid = (N + 3) / 4;

    // layer 1: 128 -> 256, relu.  Hh = fp16(relu(x@Ws1 + P@Wn1 + b1))
    agg128h<<<aggGrid, 256, 0, stream>>>(xh, csr, offs, Ph, N);
    gemm_mfma<16, 1><<<gemmGrid, 256, 0, stream>>>(xh, Ph, w1s, w1n, b1, nullptr, nullptr,
                                                   Hh, N, 128, 256, 1, 2);
    // layer 2: 256 -> 256, relu.  Hh = fp16(relu(H@Ws2 + P@Wn2 + b2))  (in place)
    agg256h<<<aggGrid, 256, 0, stream>>>(Hh, csr, offs, Ph, N);
    gemm_mfma<16, 1><<<gemmGrid, 256, 0, stream>>>(Hh, Ph, w2s, w2n, b2, nullptr, nullptr,
                                                   Hh, N, 256, 256, 1, 2);
    // layer 3: S = H@Ws3+b3 (fp32), Y = H@Wn3 (fp16) in one dual GEMM, then
    // out = S + mean-agg(Y).
    gemm_mfma<6, 2><<<gemmGrid, 256, 0, stream>>>(Hh, nullptr, w3c, nullptr, b3, S, Y,
                                                  nullptr, N, 256, 96, 0, 1);
    agg_l3<<<aggGrid, 256, 0, stream>>>(Y, S, csr, offs, out, N);
}

// Round 2
// 641.477 us; speedup vs baseline: 1.2900x; 1.0086x over previous
//
#include <hip/hip_runtime.h>

#define N_NODES 100000
#define N_EDGES 1600000

typedef __attribute__((ext_vector_type(8))) _Float16 half8;
typedef __attribute__((ext_vector_type(4))) _Float16 half4v;
typedef __attribute__((ext_vector_type(4))) float floatx4;

// ---------------- CSR build ----------------
// Pass 1: degree count + per-edge rank (removes atomics from the fill pass).

__global__ void deg_rank(const int* __restrict__ dst, int* __restrict__ deg,
                         int* __restrict__ rank, int e) {
    int i = blockIdx.x * blockDim.x + threadIdx.x;
    if (i < e) rank[i] = atomicAdd(&deg[dst[i]], 1);
}

// Multi-block exclusive scan of deg -> offs. Chunk = 2048/block. NB = 49.

__global__ __launch_bounds__(256) void scan_partial(const int* __restrict__ deg,
                                                    int* __restrict__ bsum, int n) {
    __shared__ int wsum[4];
    int t = threadIdx.x;
    int base = blockIdx.x * 2048 + t * 8;
    int tsum = 0;
    #pragma unroll
    for (int k = 0; k < 8; ++k) {
        int idx = base + k;
        tsum += (idx < n) ? deg[idx] : 0;
    }
    #pragma unroll
    for (int d = 1; d < 64; d <<= 1) tsum += __shfl_xor(tsum, d, 64);
    if ((t & 63) == 0) wsum[t >> 6] = tsum;
    __syncthreads();
    if (t == 0) bsum[blockIdx.x] = wsum[0] + wsum[1] + wsum[2] + wsum[3];
}

__global__ void scan_blocksums(const int* __restrict__ bsum, int* __restrict__ bbase, int nb) {
    int t = threadIdx.x;               // 64 threads
    int v = (t < nb) ? bsum[t] : 0;
    int s = v;
    #pragma unroll
    for (int d = 1; d < 64; d <<= 1) {
        int u = __shfl_up(s, d, 64);
        if (t >= d) s += u;
    }
    if (t < nb) bbase[t] = s - v;
    if (t == 63) bbase[nb] = s;
}

__global__ __launch_bounds__(256) void scan_write(const int* __restrict__ deg,
                                                  const int* __restrict__ bbase,
                                                  int* __restrict__ offs, int n, int nb) {
    __shared__ int wsum[4];
    int t = threadIdx.x;
    int lane = t & 63, w = t >> 6;
    int base = blockIdx.x * 2048 + t * 8;
    int v[8];
    #pragma unroll
    for (int k = 0; k < 8; ++k) {
        int idx = base + k;
        v[k] = (idx < n) ? deg[idx] : 0;
    }
    int tsum = 0;
    #pragma unroll
    for (int k = 0; k < 8; ++k) { int x = v[k]; v[k] = tsum; tsum += x; }
    int s = tsum;
    #pragma unroll
    for (int d = 1; d < 64; d <<= 1) {
        int u = __shfl_up(s, d, 64);
        if (lane >= d) s += u;
    }
    if (lane == 63) wsum[w] = s;
    __syncthreads();
    int wb = 0;
    for (int j = 0; j < w; ++j) wb += wsum[j];
    int texcl = bbase[blockIdx.x] + wb + (s - tsum);
    #pragma unroll
    for (int k = 0; k < 8; ++k) {
        int idx = base + k;
        if (idx < n) offs[idx] = texcl + v[k];
    }
    if (blockIdx.x == 0 && t == 0) offs[n] = bbase[nb];
}

// Pass 2: atomic-free CSR fill using precomputed ranks.
__global__ void fill_csr2(const int* __restrict__ src, const int* __restrict__ dst,
                          const int* __restrict__ offs, const int* __restrict__ rank,
                          int* __restrict__ csr, int e) {
    int i = blockIdx.x * blockDim.x + threadIdx.x;
    if (i < e) csr[offs[dst[i]] + rank[i]] = src[i];
}

// ---------------- x -> fp16 convert ----------------

__global__ void cvt_f16(const float4* __restrict__ in, half4v* __restrict__ oh, int n4) {
    int i = blockIdx.x * blockDim.x + threadIdx.x;
    if (i >= n4) return;
    float4 v = in[i];
    half4v h;
    h[0] = (_Float16)v.x; h[1] = (_Float16)v.y;
    h[2] = (_Float16)v.z; h[3] = (_Float16)v.w;
    oh[i] = h;
}

// ---------------- fused weight prep (all 6 weights, one launch) ----------------
// W[K][dout] fp32 -> Wt[npad][K] fp16.
// NOTE: 12288 is NOT a power of two -- use subtraction, never masking (r8 bug).

__global__ void prep_all(const float* __restrict__ ws1, const float* __restrict__ wn1,
                         const float* __restrict__ ws2, const float* __restrict__ wn2,
                         const float* __restrict__ ws3, const float* __restrict__ wn3,
                         _Float16* __restrict__ o1s, _Float16* __restrict__ o1n,
                         _Float16* __restrict__ o2s, _Float16* __restrict__ o2n,
                         _Float16* __restrict__ o3c) {
    int i = blockIdx.x * blockDim.x + threadIdx.x;
    if (i < 65536) {
        const float* W = (i < 32768) ? ws1 : wn1;
        _Float16* O = (i < 32768) ? o1s : o1n;
        int j = i & 32767;                         // 32768 = 2^15, mask ok
        int nn = j >> 7, k = j & 127;              // K=128, dout=256
        O[j] = (_Float16)W[k * 256 + nn];
    } else if (i < 196608) {
        int j = i - 65536;
        const float* W = (j < 65536) ? ws2 : wn2;
        _Float16* O = (j < 65536) ? o2s : o2n;
        j &= 65535;                                // 65536 = 2^16, mask ok
        int nn = j >> 8, k = j & 255;              // K=256, dout=256
        O[j] = (_Float16)W[k * 256 + nn];
    } else if (i < 221184) {
        int j = i - 196608;                        // [0, 24576)
        const float* W = (j < 12288) ? ws3 : wn3;
        _Float16* O = o3c + ((j < 12288) ? 0 : 12288);
        j = (j < 12288) ? j : j - 12288;           // FIX: 12288 not pow2, subtract
        int nn = j >> 8, k = j & 255;              // K=256, dout=47, npad=48
        O[j] = (nn < 47) ? (_Float16)W[k * 47 + nn] : (_Float16)0.f;
    }
}

// ---------------- mean aggregation over one 128-col fp16 plane ----------------
// Rows are 256 B. Wave per node; quarter-waves each fetch a different edge's row
// (16 lanes x 16 B = one dwordx4 per row). Depth-4/2 unroll keeps up to 4 rows
// in flight per quarter. Splitting D=256 aggregation into two plane passes
// halves the concurrent gather footprint (51.2 -> 25.6 MB) for L2 locality.

__global__ __launch_bounds__(256) void aggP(const _Float16* __restrict__ Xp,
                                            const int* __restrict__ csr,
                                            const int* __restrict__ offs,
                                            _Float16* __restrict__ Pp, int n) {
    int node = blockIdx.x * 4 + (threadIdx.x >> 6);
    int lane = threadIdx.x & 63;
    int qtr = lane >> 4;
    int sl = lane & 15;
    if (node >= n) return;
    int e0 = offs[node], e1 = offs[node + 1];
    float a[8] = {0.f, 0.f, 0.f, 0.f, 0.f, 0.f, 0.f, 0.f};
    int e = e0;
    for (; e + 16 <= e1; e += 16) {
        int s0 = csr[e + qtr];
        int s1 = csr[e + 4 + qtr];
        int s2 = csr[e + 8 + qtr];
        int s3 = csr[e + 12 + qtr];
        half8 u0 = ((const half8*)(Xp + (size_t)s0 * 128))[sl];
        half8 u1 = ((const half8*)(Xp + (size_t)s1 * 128))[sl];
        half8 u2 = ((const half8*)(Xp + (size_t)s2 * 128))[sl];
        half8 u3 = ((const half8*)(Xp + (size_t)s3 * 128))[sl];
        #pragma unroll
        for (int j = 0; j < 8; ++j) a[j] += (float)u0[j];
        #pragma unroll
        for (int j = 0; j < 8; ++j) a[j] += (float)u1[j];
        #pragma unroll
        for (int j = 0; j < 8; ++j) a[j] += (float)u2[j];
        #pragma unroll
        for (int j = 0; j < 8; ++j) a[j] += (float)u3[j];
    }
    for (; e + 8 <= e1; e += 8) {
        int s0 = csr[e + qtr];
        int s1 = csr[e + 4 + qtr];
        half8 u0 = ((const half8*)(Xp + (size_t)s0 * 128))[sl];
        half8 u1 = ((const half8*)(Xp + (size_t)s1 * 128))[sl];
        #pragma unroll
        for (int j = 0; j < 8; ++j) a[j] += (float)u0[j];
        #pragma unroll
        for (int j = 0; j < 8; ++j) a[j] += (float)u1[j];
    }
    for (; e + 4 <= e1; e += 4) {
        int s = csr[e + qtr];
        half8 u = ((const half8*)(Xp + (size_t)s * 128))[sl];
        #pragma unroll
        for (int j = 0; j < 8; ++j) a[j] += (float)u[j];
    }
    int rem = e1 - e;
    if (qtr < rem) {
        int s = csr[e + qtr];
        half8 u = ((const half8*)(Xp + (size_t)s * 128))[sl];
        #pragma unroll
        for (int j = 0; j < 8; ++j) a[j] += (float)u[j];
    }
    #pragma unroll
    for (int j = 0; j < 8; ++j) {
        a[j] += __shfl_xor(a[j], 16);
        a[j] += __shfl_xor(a[j], 32);
    }
    if (lane < 16) {
        float inv = 1.0f / fmaxf((float)(e1 - e0), 1.0f);
        half8 rh;
        #pragma unroll
        for (int j = 0; j < 8; ++j) rh[j] = (_Float16)(a[j] * inv);
        ((half8*)(Pp + (size_t)node * 128))[sl] = rh;
    }
}

// Layer-3 finish: out[node][0:47] = S[node] + mean(Y[nbrs]); wave per node,
// quarter-waves, 2 rows in flight per quarter; Y rows 96 B fp16.
__global__ __launch_bounds__(256) void agg_l3(const _Float16* __restrict__ Y,
                                              const float* __restrict__ S,
                                              const int* __restrict__ csr,
                                              const int* __restrict__ offs,
                                              float* __restrict__ out, int n) {
    int node = blockIdx.x * 4 + (threadIdx.x >> 6);
    int lane = threadIdx.x & 63;
    int qtr = lane >> 4;
    int sl = lane & 15;
    int c = sl < 12 ? sl : 11;
    if (node >= n) return;
    int e0 = offs[node], e1 = offs[node + 1];
    float a0 = 0.f, a1 = 0.f, a2 = 0.f, a3 = 0.f;
    int e = e0;
    for (; e + 8 <= e1; e += 8) {
        int s0 = csr[e + qtr];
        int s1 = csr[e + 4 + qtr];
        half4v f0 = ((const half4v*)(Y + (size_t)s0 * 48))[c];
        half4v f1 = ((const half4v*)(Y + (size_t)s1 * 48))[c];
        a0 += (float)f0[0] + (float)f1[0];
        a1 += (float)f0[1] + (float)f1[1];
        a2 += (float)f0[2] + (float)f1[2];
        a3 += (float)f0[3] + (float)f1[3];
    }
    for (; e + 4 <= e1; e += 4) {
        int s = csr[e + qtr];
        half4v f = ((const half4v*)(Y + (size_t)s * 48))[c];
        a0 += (float)f[0]; a1 += (float)f[1]; a2 += (float)f[2]; a3 += (float)f[3];
    }
    int rem = e1 - e;
    if (qtr < rem) {
        int s = csr[e + qtr];
        half4v f = ((const half4v*)(Y + (size_t)s * 48))[c];
        a0 += (float)f[0]; a1 += (float)f[1]; a2 += (float)f[2]; a3 += (float)f[3];
    }
    a0 += __shfl_xor(a0, 16); a0 += __shfl_xor(a0, 32);
    a1 += __shfl_xor(a1, 16); a1 += __shfl_xor(a1, 32);
    a2 += __shfl_xor(a2, 16); a2 += __shfl_xor(a2, 32);
    a3 += __shfl_xor(a3, 16); a3 += __shfl_xor(a3, 32);
    if (lane < 12) {
        float inv = 1.0f / fmaxf((float)(e1 - e0), 1.0f);
        float4 sv = ((const float4*)(S + (size_t)node * 48))[c];
        float r[4] = {sv.x + a0 * inv, sv.y + a1 * inv, sv.z + a2 * inv, sv.w + a3 * inv};
        #pragma unroll
        for (int k = 0; k < 4; ++k) {
            int col = c * 4 + k;
            if (col < 47) out[(size_t)node * 47 + col] = r[k];
        }
    }
}

// ---------------- MFMA GEMM (plain fp16, A direct-from-global) -------------
// out[128 x dout] = A1@W1 (+ A2@W2) + b (+relu), fp32 accumulate.
// A and (OUTFMT 1) outputs live in 128-col PLANES: element (r, k) is at
// base + (k>>7)*n*128 + r*128 + (k&127). Per k-step k02 is 32-aligned so the
// plane index is uniform within a step. B staged in LDS (LDT=36) with register
// prefetch of step s+1 issued after the barrier.
// OUTFMT 1: fp16 plane write (dout=256). OUTFMT 2: cols 0-47 -> S fp32 (+bias),
// cols 48-95 -> Y fp16 (stride 48).

template <int NTILES, int OUTFMT>
__global__ __launch_bounds__(256, 2) void gemm_mfma(
    const _Float16* __restrict__ A1h, const _Float16* __restrict__ A2h,
    const _Float16* __restrict__ W1, const _Float16* __restrict__ W2,
    const float* __restrict__ bias, float* __restrict__ outS, _Float16* __restrict__ outY,
    _Float16* __restrict__ outh, int n, int K, int dout, int relu, int phases) {
    constexpr int NPAD = NTILES * 16;
    constexpr int LDT = 36;
    __shared__ _Float16 Bs[NPAD * LDT];

    const int t = threadIdx.x;
    const int bm = blockIdx.x * 128;
    const int lane = t & 63;
    const int w = t >> 6;
    const int quad = lane >> 4;
    const int tl = lane & 15;
    const int r0 = bm + w * 32 + tl;
    const int r1 = r0 + 16;
    const size_t PS = (size_t)n * 128;   // plane stride

    floatx4 acc[2][NTILES];
    #pragma unroll
    for (int i = 0; i < 2; ++i)
        #pragma unroll
        for (int j = 0; j < NTILES; ++j) acc[i][j] = (floatx4){0.f, 0.f, 0.f, 0.f};

    const int spp = K >> 5;
    const int nsteps = phases * spp;

    half8 pb0, pb1, pb2, pb3;
    half8 pah0 = {0}, pah1 = {0};

    if (t < NPAD) {
        const half8* p = (const half8*)(W1 + (size_t)t * K);
        pb0 = p[0]; pb1 = p[1]; pb2 = p[2]; pb3 = p[3];
    }
    {
        int kq = quad * 8;               // step 0: k < 32 -> plane 0
        if (r0 < n) pah0 = *(const half8*)(A1h + (size_t)r0 * 128 + kq);
        if (r1 < n) pah1 = *(const half8*)(A1h + (size_t)r1 * 128 + kq);
    }

    for (int s = 0; s < nsteps; ++s) {
        __syncthreads();
        if (t < NPAD) {
            *(half8*)&Bs[t * LDT + 0]  = pb0;
            *(half8*)&Bs[t * LDT + 8]  = pb1;
            *(half8*)&Bs[t * LDT + 16] = pb2;
            *(half8*)&Bs[t * LDT + 24] = pb3;
        }
        __syncthreads();
        half8 ah0 = pah0, ah1 = pah1;
        if (s + 1 < nsteps) {
            int s2 = s + 1;
            int ph2 = (s2 >= spp) ? 1 : 0;
            int k02 = (ph2 ? s2 - spp : s2) << 5;
            if (t < NPAD) {
                const _Float16* W = ph2 ? W2 : W1;
                const half8* p = (const half8*)(W + (size_t)t * K + k02);
                pb0 = p[0]; pb1 = p[1]; pb2 = p[2]; pb3 = p[3];
            }
            const _Float16* Ah = ph2 ? A2h : A1h;
            int kq = k02 + quad * 8;
            const _Float16* Ab = Ah + ((kq >> 7) ? PS : (size_t)0) + (kq & 127);
            pah0 = (half8){0}; pah1 = (half8){0};
            if (r0 < n) pah0 = *(const half8*)(Ab + (size_t)r0 * 128);
            if (r1 < n) pah1 = *(const half8*)(Ab + (size_t)r1 * 128);
        }
        #pragma unroll
        for (int nt = 0; nt < NTILES; ++nt) {
            half8 bh = *(const half8*)&Bs[(nt * 16 + tl) * LDT + quad * 8];
            acc[0][nt] = __builtin_amdgcn_mfma_f32_16x16x32_f16(ah0, bh, acc[0][nt], 0, 0, 0);
            acc[1][nt] = __builtin_amdgcn_mfma_f32_16x16x32_f16(ah1, bh, acc[1][nt], 0, 0, 0);
        }
    }

    #pragma unroll
    for (int mt = 0; mt < 2; ++mt) {
        #pragma unroll
        for (int nt = 0; nt < NTILES; ++nt) {
            int gc = nt * 16 + tl;
            if (OUTFMT == 1 && gc >= dout) continue;
            #pragma unroll
            for (int r = 0; r < 4; ++r) {
                int gr = bm + w * 32 + mt * 16 + quad * 4 + r;
                if (gr >= n) continue;
                float v = acc[mt][nt][r];
                if (OUTFMT == 1) {
                    v += bias[gc];
                    if (relu) v = fmaxf(v, 0.f);
                    outh[(size_t)(gc >> 7) * PS + (size_t)gr * 128 + (gc & 127)] = (_Float16)v;
                } else {
                    if (gc < 48) {
                        v += (gc < 47) ? bias[gc] : 0.f;
                        outS[(size_t)gr * 48 + gc] = v;
                    } else {
                        outY[(size_t)gr * 48 + (gc - 48)] = (_Float16)v;
                    }
                }
            }
        }
    }
}

extern "C" void kernel_launch(void* const* d_in, const int* in_sizes, int n_in,
                              void* d_out, int out_size, void* d_ws, size_t ws_size,
                              hipStream_t stream) {
    (void)in_sizes; (void)n_in; (void)out_size; (void)ws_size;
    const int N = N_NODES, E = N_EDGES;
    const float* x = (const float*)d_in[0];
    const int* src = (const int*)d_in[1];
    const int* dst = (const int*)d_in[2];
    const float* w_self1 = (const float*)d_in[3];
    const float* w_neigh1 = (const float*)d_in[4];
    const float* b1 = (const float*)d_in[5];
    const float* w_self2 = (const float*)d_in[6];
    const float* w_neigh2 = (const float*)d_in[7];
    const float* b2 = (const float*)d_in[8];
    const float* w_self3 = (const float*)d_in[9];
    const float* w_neigh3 = (const float*)d_in[10];
    const float* b3 = (const float*)d_in[11];
    float* out = (float*)d_out;

    // workspace layout (~110 MB)
    _Float16* Ph = (_Float16*)d_ws;             // N*256 fp16 (P planes P0|P1)
    _Float16* Hh = Ph + (size_t)N * 256;        // N*256 fp16 (H planes H0|H1)
    int* deg = (int*)(Hh + (size_t)N * 256);    // N
    int* offs = deg + N;                        // N+4
    int* csr = offs + N + 4;                    // E
    _Float16* wbuf = (_Float16*)(csr + E);
    _Float16* w1s = wbuf;                       // 256*128
    _Float16* w1n = w1s + 32768;                // 256*128
    _Float16* w2s = w1n + 32768;                // 256*256
    _Float16* w2n = w2s + 65536;                // 256*256
    _Float16* w3c = w2n + 65536;                // 96*256 combined [self|neigh]
    int* bsum = (int*)(w3c + 24576);            // 64
    int* bbase = bsum + 64;                     // NB+1
    // overlays on the Ph region:
    int* rank = (int*)Ph;                       // E ints, dead before aggP writes P0
    _Float16* xh = Ph + (size_t)N * 128;        // N*128 fp16 (layer 1; dead after gemm1)
    float* S = (float*)Ph;                      // N*48 fp32 (layer 3; P dead)
    _Float16* Y = (_Float16*)(S + (size_t)N * 48);  // N*48 fp16

    const int NB = (N + 2047) / 2048;           // 49 scan blocks

    hipMemsetAsync(deg, 0, N * sizeof(int), stream);
    deg_rank<<<(E + 255) / 256, 256, 0, stream>>>(dst, deg, rank, E);
    scan_partial<<<NB, 256, 0, stream>>>(deg, bsum, N);
    scan_blocksums<<<1, 64, 0, stream>>>(bsum, bbase, NB);
    scan_write<<<NB, 256, 0, stream>>>(deg, bbase, offs, N, NB);
    fill_csr2<<<(E + 255) / 256, 256, 0, stream>>>(src, dst, offs, rank, csr, E);

    cvt_f16<<<(N * 128 / 4 + 255) / 256, 256, 0, stream>>>((const float4*)x, (half4v*)xh,
                                                           N * 128 / 4);
    prep_all<<<(221184 + 255) / 256, 256, 0, stream>>>(w_self1, w_neigh1, w_self2, w_neigh2,
                                                       w_self3, w_neigh3, w1s, w1n, w2s, w2n,
                                                       w3c);

    int gemmGrid = (N + 127) / 128;
    int aggGrid = (N + 3) / 4;

    // layer 1: 128 -> 256, relu.  H planes = fp16(relu(x@Ws1 + P@Wn1 + b1))
    aggP<<<aggGrid, 256, 0, stream>>>(xh, csr, offs, Ph, N);
    gemm_mfma<16, 1><<<gemmGrid, 256, 0, stream>>>(xh, Ph, w1s, w1n, b1, nullptr, nullptr,
                                                   Hh, N, 128, 256, 1, 2);
    // layer 2: 256 -> 256, relu, in place.  Aggregate each H plane separately
    // (temporal split halves the concurrent gather footprint for L2 locality).
    aggP<<<aggGrid, 256, 0, stream>>>(Hh, csr, offs, Ph, N);
    aggP<<<aggGrid, 256, 0, stream>>>(Hh + (size_t)N * 128, csr, offs, Ph + (size_t)N * 128, N);
    gemm_mfma<16, 1><<<gemmGrid, 256, 0, stream>>>(Hh, Ph, w2s, w2n, b2, nullptr, nullptr,
                                                   Hh, N, 256, 256, 1, 2);
    // layer 3: S = H@Ws3+b3 (fp32), Y = H@Wn3 (fp16) in one dual GEMM, then
    // out = S + mean-agg(Y).
    gemm_mfma<6, 2><<<gemmGrid, 256, 0, stream>>>(Hh, nullptr, w3c, nullptr, b3, S, Y,
                                                  nullptr, N, 256, 96, 0, 1);
    agg_l3<<<aggGrid, 256, 0, stream>>>(Y, S, csr, offs, out, N);
}